// Round 12
// baseline (217.075 us; speedup 1.0000x reference)
//
#include <hip/hip_runtime.h>
#include <stdint.h>

#define S_   512
#define E_   512
#define CIN  1536
#define P_   32768
#define OUTC 512
#define LDP  40    // padded LDS row stride (shorts) for gemm_g register-staged tiles
#define LDA3 40    // gemm2 BK=32 A-tile stride (shorts): 32 + 8 pad -> 2-way-free b128
#define CST2 264   // gemm2 epilogue C-staging stride (shorts): 256 + 8
#define GSLAB ((size_t)4 * S_ * OUTC)   // one K-slab of G: [4 batches][512][512] fp32

typedef __attribute__((ext_vector_type(8))) short s16x8;   // MFMA A/B frag (8 bf16)
typedef __attribute__((ext_vector_type(4))) float f32x4;   // MFMA C/D frag
typedef unsigned short ushort_t;

__device__ __forceinline__ float b2f(uint32_t b) {
    union { uint32_t u; float f; } v; v.u = b << 16; return v.f;
}
__device__ __forceinline__ uint32_t f2b(float f) {   // fp32 -> bf16 bits, RNE
    union { float f; uint32_t u; } v; v.f = f;
    return (v.u + 0x7fffu + ((v.u >> 16) & 1u)) >> 16;
}
__device__ __forceinline__ uint4 cvt8(float4 a, float4 b) {
    uint4 r;
    r.x = f2b(a.x) | (f2b(a.y) << 16);
    r.y = f2b(a.z) | (f2b(a.w) << 16);
    r.z = f2b(b.x) | (f2b(b.y) << 16);
    r.w = f2b(b.z) | (f2b(b.w) << 16);
    return r;
}
__device__ __forceinline__ void async16(const void* g, void* l) {
    __builtin_amdgcn_global_load_lds(
        (const __attribute__((address_space(1))) void*)g,
        (__attribute__((address_space(3))) void*)l, 16, 0, 0);
}
// branchless top-3 insert
__device__ __forceinline__ void ins3(float d, int s,
                                     float& d0, int& i0, float& d1, int& i1,
                                     float& d2, int& i2)
{
    const bool c0 = d < d0, c1 = d < d1, c2 = d < d2;
    i2 = c1 ? i1 : (c2 ? s : i2);  d2 = c1 ? d1 : (c2 ? d : d2);
    i1 = c0 ? i0 : (c1 ? s : i1);  d1 = c0 ? d0 : (c1 ? d : d1);
    i0 = c0 ? s  : i0;             d0 = c0 ? d  : d0;
}

// ---------- 1) stage1: gemm_g ∥ W2-convert ∥ stats-zero ∥ kNN — one dispatch ----------
// Block map: [0,768) gemm_g | [768,1024) W2 cvt | 1024 stats zero | [1025,1537) kNN.
// gemm_g converts W1 inline and writes per-K-chunk slabs G0/G1/G2 with PLAIN stores.
__global__ __launch_bounds__(256) void stage1_kernel(
    const float* __restrict__ xyz, const float* __restrict__ centers,
    const float* __restrict__ W1f, const float* __restrict__ W2f,
    ushort_t* __restrict__ W2c,
    int* __restrict__ idx_out, float* __restrict__ w_out, float* __restrict__ stats,
    const float* __restrict__ H4, const float* __restrict__ H8,
    const float* __restrict__ H12, float* __restrict__ G)
{
    __shared__ float4 c4[S_];
    __shared__ ushort_t Asm[64 * LDP];
    __shared__ ushort_t Bsm[64 * LDP];
    const int blk = blockIdx.x;
    const int t   = threadIdx.x;

    if (blk < 768) {
        // ================= gemm_g role: G_ck[b] = H_ck[b] x W1_ck^T =================
        const int gblk = blk;                   // 0..767
        const int bz = gblk >> 6;               // 0..11  (bb*3 + ck)
        const int rem = gblk & 63;
        const int colBase = (rem & 7) * 64, rowBase = (rem >> 3) * 64;
        const int bb = bz / 3, ck = bz - bb * 3;
        const float* Hs = (ck == 0 ? H4 : (ck == 1) ? H8 : H12) + (size_t)bb * S_ * E_;
        const int kOff = ck * 512;
        const int wave = t >> 6, lane = t & 63;
        const int wr = wave >> 1, wc = wave & 1, quad = lane >> 4, l15 = lane & 15;

        f32x4 acc[2][2];
        const f32x4 z4 = {0.f, 0.f, 0.f, 0.f};
#pragma unroll
        for (int i = 0; i < 2; ++i)
#pragma unroll
            for (int j = 0; j < 2; ++j) acc[i][j] = z4;

        const int ar = t >> 2, ac = (t & 3) * 8;

        float4 A0a, A0b, B0a, B0b;
        auto loadTile = [&](int k0) {
            const int kc = k0 + ac;
            const float* r0 = Hs + (size_t)(rowBase + ar) * E_ + kc;
            A0a = *(const float4*)r0;  A0b = *(const float4*)(r0 + 4);
            const float* w0 = W1f + (size_t)(colBase + ar) * CIN + kOff + kc;
            B0a = *(const float4*)w0;  B0b = *(const float4*)(w0 + 4);
        };
        loadTile(0);

        for (int k0 = 0; k0 < 512; k0 += 32) {
            __syncthreads();
            *(uint4*)&Asm[ar * LDP + ac] = cvt8(A0a, A0b);
            *(uint4*)&Bsm[ar * LDP + ac] = cvt8(B0a, B0b);
            __syncthreads();
            if (k0 + 32 < 512) loadTile(k0 + 32);

            s16x8 af[2], bfr[2];
#pragma unroll
            for (int mi = 0; mi < 2; ++mi)
                af[mi] = *(const s16x8*)&Asm[(wr * 32 + mi * 16 + l15) * LDP + quad * 8];
#pragma unroll
            for (int ni = 0; ni < 2; ++ni)
                bfr[ni] = *(const s16x8*)&Bsm[(wc * 32 + ni * 16 + l15) * LDP + quad * 8];
#pragma unroll
            for (int mi = 0; mi < 2; ++mi)
#pragma unroll
                for (int ni = 0; ni < 2; ++ni)
                    acc[mi][ni] = __builtin_amdgcn_mfma_f32_16x16x32_bf16(
                        af[mi], bfr[ni], acc[mi][ni], 0, 0, 0);
        }

        float* Gs = G + (size_t)ck * GSLAB;
#pragma unroll
        for (int mi = 0; mi < 2; ++mi) {
            const int row0 = rowBase + wr * 32 + mi * 16 + quad * 4;
#pragma unroll
            for (int ni = 0; ni < 2; ++ni) {
                const int col = colBase + wc * 32 + ni * 16 + l15;
#pragma unroll
                for (int r = 0; r < 4; ++r)
                    Gs[((size_t)bb * S_ + row0 + r) * OUTC + col] = acc[mi][ni][r];
            }
        }
        return;
    }

    if (blk < 1025) {
        if (blk < 1024) {          // W2: 65536 vec4 over 256 blocks
            const int v = (blk - 768) * 256 + t;
            const float4 x = ((const float4*)W2f)[v];
            uint2 o; o.x = f2b(x.x) | (f2b(x.y) << 16); o.y = f2b(x.z) | (f2b(x.w) << 16);
            ((uint2*)W2c)[v] = o;
        } else {                   // blk == 1024: zero 2048-float stats
#pragma unroll
            for (int i = 0; i < 8; ++i) stats[t * 8 + i] = 0.f;
        }
        return;
    }

    // ================= kNN role: 4 lanes/point, dual top-3 chains =================
    const int pBlock = (blk - 1025) * 64;
    const int b = pBlock >> 13;
    for (int i = t; i < S_; i += 256) {
        const float x = centers[(size_t)(b * S_ + i) * 3 + 0];
        const float y = centers[(size_t)(b * S_ + i) * 3 + 1];
        const float z = centers[(size_t)(b * S_ + i) * 3 + 2];
        float4 v; v.x = x; v.y = y; v.z = z; v.w = x * x + y * y + z * z;
        c4[i] = v;
    }
    __syncthreads();

    const int l4 = t & 3, pi = t >> 2;
    const int p = pBlock + pi;
    const float x = xyz[(size_t)p * 3 + 0];
    const float y = xyz[(size_t)p * 3 + 1];
    const float z = xyz[(size_t)p * 3 + 2];
    const float xx = x * x + y * y + z * z;

    float d0 = 3e38f, d1 = 3e38f, d2 = 3e38f;
    int   i0 = 0,     i1 = 0,     i2 = 0;
    float e0 = 3e38f, e1 = 3e38f, e2 = 3e38f;
    int   f0 = 0,     f1 = 0,     f2 = 0;
#pragma unroll 2
    for (int j = 0; j < 128; j += 2) {
        const int sA = 4 * j + l4;
        const int sB = sA + 4;
        const float4 cA = c4[sA];
        const float4 cB = c4[sB];
        const float dotA = x * cA.x + y * cA.y + z * cA.z;
        const float dotB = x * cB.x + y * cB.y + z * cB.z;
        const float dA = (xx - 2.0f * dotA) + cA.w;   // mirror np association
        const float dB = (xx - 2.0f * dotB) + cB.w;
        ins3(dA, sA, d0, i0, d1, i1, d2, i2);
        ins3(dB, sB, e0, f0, e1, f1, e2, f2);
    }
    ins3(e0, f0, d0, i0, d1, i1, d2, i2);
    ins3(e1, f1, d0, i0, d1, i1, d2, i2);
    ins3(e2, f2, d0, i0, d1, i1, d2, i2);
#pragma unroll
    for (int m = 1; m <= 2; m <<= 1) {
        const float od0 = __shfl_xor(d0, m), od1 = __shfl_xor(d1, m), od2 = __shfl_xor(d2, m);
        const int   oi0 = __shfl_xor(i0, m), oi1 = __shfl_xor(i1, m), oi2 = __shfl_xor(i2, m);
        ins3(od0, oi0, d0, i0, d1, i1, d2, i2);
        ins3(od1, oi1, d0, i0, d1, i1, d2, i2);
        ins3(od2, oi2, d0, i0, d1, i1, d2, i2);
    }
    if (l4 == 0) {
        const float r0 = 1.0f / (d0 + 1e-8f);
        const float r1 = 1.0f / (d1 + 1e-8f);
        const float r2 = 1.0f / (d2 + 1e-8f);
        const float rs = r0 + r1 + r2;
        idx_out[p * 3 + 0] = i0; idx_out[p * 3 + 1] = i1; idx_out[p * 3 + 2] = i2;
        w_out[p * 3 + 0] = r0 / rs; w_out[p * 3 + 1] = r1 / rs; w_out[p * 3 + 2] = r2 / rs;
    }
}

// ---------- 2) greduce: G0 += G1 + G2 (dense, coalesced; 12 MB read + 4 MB write) ----------
__global__ __launch_bounds__(256) void greduce_kernel(float4* __restrict__ G)
{
    const float4* G1 = G + GSLAB / 4;
    const float4* G2 = G + 2 * (GSLAB / 4);
    const size_t v0 = ((size_t)blockIdx.x * 256 + threadIdx.x) * 2;
#pragma unroll
    for (int i = 0; i < 2; ++i) {
        const size_t v = v0 + i;
        float4 a = G[v];
        const float4 b = G1[v];
        const float4 c = G2[v];
        a.x += b.x + c.x; a.y += b.y + c.y; a.z += b.z + c.z; a.w += b.w + c.w;
        G[v] = a;
    }
}

// ---------- 3) blend: C1raw[p] = sum_k w_k * G[b,i_k] (fp32) -> bf16 + BN1 stats ----------
// v3 (isolated r6 change): 1024 blocks x 32 points = 4 blocks/CU (4 waves/SIMD, was 2)
// + idx/wgt prefetched one iteration ahead. blend1 is latency-bound on L2 gathers
// (G is 4 MB, L2-resident); doubling resident waves halves the exposed gather latency.
__global__ __launch_bounds__(256) void blend1(
    const float* __restrict__ G, const int* __restrict__ idx, const float* __restrict__ wgt,
    ushort_t* __restrict__ C1, float* __restrict__ gsum, float* __restrict__ gsq)
{
    __shared__ float reds[512], redq[512];
    const int t = threadIdx.x;
    const int cg = t & 63, pr = t >> 6;
    const int ch0 = cg * 8;
    const int pBase = blockIdx.x * 32;

    float s[8], q[8];
#pragma unroll
    for (int e = 0; e < 8; ++e) { s[e] = 0.f; q[e] = 0.f; }

    int ni0, ni1, ni2; float nw0, nw1, nw2;
    {
        const int p0 = pBase + pr;
        ni0 = idx[p0 * 3 + 0]; ni1 = idx[p0 * 3 + 1]; ni2 = idx[p0 * 3 + 2];
        nw0 = wgt[p0 * 3 + 0]; nw1 = wgt[p0 * 3 + 1]; nw2 = wgt[p0 * 3 + 2];
    }
#pragma unroll
    for (int j = 0; j < 8; ++j) {
        const int p = pBase + j * 4 + pr;
        const int b = p >> 13;
        const int i0 = ni0, i1 = ni1, i2 = ni2;
        const float w0 = nw0, w1 = nw1, w2 = nw2;
        if (j < 7) {               // prefetch next iteration's indices/weights
            const int pn = p + 4;
            ni0 = idx[pn * 3 + 0]; ni1 = idx[pn * 3 + 1]; ni2 = idx[pn * 3 + 2];
            nw0 = wgt[pn * 3 + 0]; nw1 = wgt[pn * 3 + 1]; nw2 = wgt[pn * 3 + 2];
        }
        const float* g0 = G + ((size_t)b * S_ + i0) * OUTC + ch0;
        const float* g1 = G + ((size_t)b * S_ + i1) * OUTC + ch0;
        const float* g2 = G + ((size_t)b * S_ + i2) * OUTC + ch0;
        float c[8];
        uint32_t od[4];
#pragma unroll
        for (int e = 0; e < 8; ++e) {
            c[e] = w0 * g0[e] + w1 * g1[e] + w2 * g2[e];
            s[e] += c[e]; q[e] += c[e] * c[e];
        }
#pragma unroll
        for (int e = 0; e < 4; ++e) od[e] = f2b(c[2 * e]) | (f2b(c[2 * e + 1]) << 16);
        uint4 o; o.x = od[0]; o.y = od[1]; o.z = od[2]; o.w = od[3];
        *(uint4*)(C1 + (size_t)p * OUTC + ch0) = o;
    }

    for (int i = t; i < 512; i += 256) { reds[i] = 0.f; redq[i] = 0.f; }
    __syncthreads();
#pragma unroll
    for (int e = 0; e < 8; ++e) {
        atomicAdd(&reds[ch0 + e], s[e]);
        atomicAdd(&redq[ch0 + e], q[e]);
    }
    __syncthreads();
    for (int i = t; i < 512; i += 256) {
        atomicAdd(&gsum[i], reds[i]);
        atomicAdd(&gsq[i],  redq[i]);
    }
}

// ---------- 4) GEMM2: BK=32 double-buffered pipeline (r9/r11 exact) ----------
__global__ __launch_bounds__(512, 4) void gemm2_fused(
    const ushort_t* __restrict__ Araw, const ushort_t* __restrict__ Bw,
    float* __restrict__ outF, ushort_t* __restrict__ outB, int out_bf16,
    const float* __restrict__ gsum1, const float* __restrict__ gsq1,
    const float* __restrict__ g1, const float* __restrict__ be1,
    float* __restrict__ gsum2, float* __restrict__ gsq2)
{
    __shared__ __align__(16) ushort_t sbuf[26624];
    __shared__ float sc1[512], sh1[512];
    __shared__ float red[512];
    ushort_t* const Asm0 = sbuf;
    ushort_t* const Asm1 = sbuf + 5120;
    ushort_t* const Bsm0 = sbuf + 10240;
    ushort_t* const Bsm1 = sbuf + 18432;

    const int K = 512, Nn = 512;
    const int t = threadIdx.x, wave = t >> 6, lane = t & 63;
    const int wr = wave >> 2, wc = wave & 3, quad = lane >> 4, l15 = lane & 15;
    const int rowBase = blockIdx.x * 128, colBase = blockIdx.y * 256;

    {
        const float inv = 1.0f / (float)P_;
        const float mean = gsum1[t] * inv;
        const float var  = gsq1[t] * inv - mean * mean;
        const float s    = g1[t] * rsqrtf(var + 1e-5f);
        sc1[t] = s; sh1[t] = be1[t] - mean * s;
    }

    f32x4 acc[4][4];
    const f32x4 z4 = {0.f, 0.f, 0.f, 0.f};
#pragma unroll
    for (int i = 0; i < 4; ++i)
#pragma unroll
        for (int j = 0; j < 4; ++j) acc[i][j] = z4;

    const int ar  = t >> 2;
    const int ac8 = (t & 3) * 8;
    const ushort_t* Ab = Araw + (size_t)rowBase * K;

    // B DMA: 2 issues/thread/step; XOR class (row>>1)&3 == (lane>>3)&3 for both issues.
    const int brow = wave * 32 + (lane >> 2);
    const int bq8  = ((lane & 3) ^ ((lane >> 3) & 3)) * 8;
    const int bdst = wave * 1024 + lane * 8;
    const ushort_t* Bb = Bw + (size_t)colBase * K;

    auto xform = [&](const uint4 a, const int k0n, ushort_t* dst) {
        const int c0 = k0n + ac8;
        const float4 sa = *(const float4*)&sc1[c0], sb = *(const float4*)&sc1[c0 + 4];
        const float4 ha = *(const float4*)&sh1[c0], hb = *(const float4*)&sh1[c0 + 4];
        const float y0 = fmaxf(0.f, b2f(a.x & 0xffffu) * sa.x + ha.x);
        const float y1 = fmaxf(0.f, b2f(a.x >> 16)     * sa.y + ha.y);
        const float y2 = fmaxf(0.f, b2f(a.y & 0xffffu) * sa.z + ha.z);
        const float y3 = fmaxf(0.f, b2f(a.y >> 16)     * sa.w + ha.w);
        const float y4 = fmaxf(0.f, b2f(a.z & 0xffffu) * sb.x + hb.x);
        const float y5 = fmaxf(0.f, b2f(a.z >> 16)     * sb.y + hb.y);
        const float y6 = fmaxf(0.f, b2f(a.w & 0xffffu) * sb.z + hb.z);
        const float y7 = fmaxf(0.f, b2f(a.w >> 16)     * sb.w + hb.w);
        uint4 u;
        u.x = f2b(y0) | (f2b(y1) << 16); u.y = f2b(y2) | (f2b(y3) << 16);
        u.z = f2b(y4) | (f2b(y5) << 16); u.w = f2b(y6) | (f2b(y7) << 16);
        *(uint4*)&dst[ar * LDA3 + ac8] = u;
    };

    uint4 aA = *(const uint4*)(Ab + (size_t)ar * K + ac8);
    __syncthreads();

    async16(Bb + (size_t)brow * K + bq8,        Bsm0 + bdst);
    async16(Bb + (size_t)(brow + 16) * K + bq8, Bsm0 + bdst + 512);
    xform(aA, 0, Asm0);
    uint4 aB = *(const uint4*)(Ab + (size_t)ar * K + 32 + ac8);
    __syncthreads();

#pragma unroll
    for (int k = 0; k < 16; ++k) {
        ushort_t* const Asmb = (k & 1) ? Asm1 : Asm0;
        ushort_t* const Bsmb = (k & 1) ? Bsm1 : Bsm0;
        ushort_t* const AsmN = (k & 1) ? Asm0 : Asm1;
        ushort_t* const BsmN = (k & 1) ? Bsm0 : Bsm1;
        if (k < 15) {
            const int k0n = (k + 1) * 32;
            async16(Bb + (size_t)brow * K + k0n + bq8,        BsmN + bdst);
            async16(Bb + (size_t)(brow + 16) * K + k0n + bq8, BsmN + bdst + 512);
            if (k < 14) {
                const int k0p = (k + 2) * 32;
                if (k & 1) aB = *(const uint4*)(Ab + (size_t)ar * K + k0p + ac8);
                else       aA = *(const uint4*)(Ab + (size_t)ar * K + k0p + ac8);
            }
            xform((k & 1) ? aA : aB, k0n, AsmN);
        }
        s16x8 af[4], bfr[4];
#pragma unroll
        for (int mi = 0; mi < 4; ++mi)
            af[mi] = *(const s16x8*)&Asmb[(wr * 64 + mi * 16 + l15) * LDA3 + quad * 8];
#pragma unroll
        for (int ni = 0; ni < 4; ++ni) {
            const int r = wc * 64 + ni * 16 + l15;
            bfr[ni] = *(const s16x8*)&Bsmb[r * 32 + ((quad ^ ((r >> 1) & 3)) << 3)];
        }
#pragma unroll
        for (int mi = 0; mi < 4; ++mi)
#pragma unroll
            for (int ni = 0; ni < 4; ++ni)
                acc[mi][ni] = __builtin_amdgcn_mfma_f32_16x16x32_bf16(
                    af[mi], bfr[ni], acc[mi][ni], 0, 0, 0);
        __syncthreads();
    }

    // ---- BN2 stats (cols colBase..colBase+255) ----
    red[t] = 0.f;
    __syncthreads();
#pragma unroll
    for (int ni = 0; ni < 4; ++ni) {
        float s = 0.f, q = 0.f;
#pragma unroll
        for (int mi = 0; mi < 4; ++mi)
#pragma unroll
            for (int r = 0; r < 4; ++r) { const float v = acc[mi][ni][r]; s += v; q += v * v; }
        const int cl = wc * 64 + ni * 16 + l15;
        atomicAdd(&red[cl], s);
        atomicAdd(&red[256 + cl], q);
    }
    __syncthreads();
    if (t < 256) atomicAdd(&gsum2[colBase + t], red[t]);
    else         atomicAdd(&gsq2[colBase + (t - 256)], red[t]);

    // ---- store: LDS-staged coalesced (bf16 path) ----
    if (out_bf16) {
        ushort_t* cst = sbuf;
        const int rr = t >> 3, seg = t & 7;
#pragma unroll
        for (int c = 0; c < 2; ++c) {
            __syncthreads();
            if (wr == c) {
#pragma unroll
                for (int mi = 0; mi < 4; ++mi)
#pragma unroll
                    for (int ni = 0; ni < 4; ++ni)
#pragma unroll
                        for (int r = 0; r < 4; ++r)
                            cst[(mi * 16 + quad * 4 + r) * CST2 + wc * 64 + ni * 16 + l15] =
                                (ushort_t)f2b(acc[mi][ni][r]);
            }
            __syncthreads();
            const size_t gbase = (size_t)(rowBase + c * 64 + rr) * Nn + colBase;
#pragma unroll
            for (int i = 0; i < 4; ++i) {
                const int cc = seg + i * 8;
                const uint4 v = *(const uint4*)&cst[rr * CST2 + cc * 8];
                *(uint4*)(outB + gbase + cc * 8) = v;
            }
        }
    } else {
#pragma unroll
        for (int mi = 0; mi < 4; ++mi) {
            const int row0 = rowBase + wr * 64 + mi * 16 + quad * 4;
#pragma unroll
            for (int ni = 0; ni < 4; ++ni) {
                const int col = colBase + wc * 64 + ni * 16 + l15;
#pragma unroll
                for (int r = 0; r < 4; ++r)
                    outF[(size_t)(row0 + r) * Nn + col] = acc[mi][ni][r];
            }
        }
    }
}

// ---------- 5) BN2 finalize + apply + ReLU -> d_out fp32 (grid-stride, 2048 blocks) ----------
__global__ __launch_bounds__(256) void bn_apply_out(
    const ushort_t* __restrict__ C2, float* __restrict__ Y,
    const float* __restrict__ gsum, const float* __restrict__ gsq,
    const float* __restrict__ gamma, const float* __restrict__ beta, int from_bf16)
{
    __shared__ float sc[512], sh[512];
    const int t = threadIdx.x;
    const float inv = 1.0f / (float)P_;
    for (int i = t; i < 512; i += 256) {
        const float mean = gsum[i] * inv;
        const float var  = gsq[i] * inv - mean * mean;
        const float s    = gamma[i] * rsqrtf(var + 1e-5f);
        sc[i] = s; sh[i] = beta[i] - mean * s;
    }
    __syncthreads();
    const size_t total = (size_t)P_ * OUTC / 8;
    for (size_t v = (size_t)blockIdx.x * 256 + t; v < total; v += (size_t)2048 * 256) {
        const int ch = (int)((v * 8) & 511);
        float4 u0, u1;
        if (from_bf16) {
            const uint4 xv = ((const uint4*)C2)[v];
            u0.x = b2f(xv.x & 0xffffu); u0.y = b2f(xv.x >> 16);
            u0.z = b2f(xv.y & 0xffffu); u0.w = b2f(xv.y >> 16);
            u1.x = b2f(xv.z & 0xffffu); u1.y = b2f(xv.z >> 16);
            u1.z = b2f(xv.w & 0xffffu); u1.w = b2f(xv.w >> 16);
        } else {
            u0 = ((const float4*)Y)[v * 2];
            u1 = ((const float4*)Y)[v * 2 + 1];
        }
        u0.x = fmaxf(0.f, u0.x * sc[ch + 0] + sh[ch + 0]);
        u0.y = fmaxf(0.f, u0.y * sc[ch + 1] + sh[ch + 1]);
        u0.z = fmaxf(0.f, u0.z * sc[ch + 2] + sh[ch + 2]);
        u0.w = fmaxf(0.f, u0.w * sc[ch + 3] + sh[ch + 3]);
        u1.x = fmaxf(0.f, u1.x * sc[ch + 4] + sh[ch + 4]);
        u1.y = fmaxf(0.f, u1.y * sc[ch + 5] + sh[ch + 5]);
        u1.z = fmaxf(0.f, u1.z * sc[ch + 6] + sh[ch + 6]);
        u1.w = fmaxf(0.f, u1.w * sc[ch + 7] + sh[ch + 7]);
        ((float4*)Y)[v * 2]     = u0;
        ((float4*)Y)[v * 2 + 1] = u1;
    }
}

// ---------- launch ----------
extern "C" void kernel_launch(void* const* d_in, const int* in_sizes, int n_in,
                              void* d_out, int out_size, void* d_ws, size_t ws_size,
                              hipStream_t stream)
{
    (void)in_sizes; (void)n_in; (void)out_size;
    const float* xyzF = (const float*)d_in[0];
    const float* cenF = (const float*)d_in[1];
    const float* H4   = (const float*)d_in[2];
    const float* H8   = (const float*)d_in[3];
    const float* H12  = (const float*)d_in[4];
    const float* W1f  = (const float*)d_in[5];
    // b1 (d_in[6]) / b2 (d_in[10]) cancel in BN mean subtraction
    const float* g1F  = (const float*)d_in[7];
    const float* be1F = (const float*)d_in[8];
    const float* W2f  = (const float*)d_in[9];
    const float* g2F  = (const float*)d_in[11];
    const float* be2F = (const float*)d_in[12];

    char* w = (char*)d_ws;
    float*    stats = (float*)w;     w += 2048 * 4;
    ushort_t* W2c   = (ushort_t*)w;  w += (size_t)OUTC * OUTC * 2;
    int*      idxb  = (int*)w;       w += (size_t)P_ * 3 * 4;
    float*    wb    = (float*)w;     w += (size_t)P_ * 3 * 4;
    float*    G     = (float*)w;     w += 3 * GSLAB * 4;               // 12 MB (3 K-slabs)
    ushort_t* C1    = (ushort_t*)w;  w += (size_t)P_ * OUTC * 2;       // 32 MB (raw, pre-BN)
    const size_t need1 = (size_t)(w - (char*)d_ws);
    const int out_bf16 = (ws_size >= need1 + (size_t)P_ * OUTC * 2) ? 1 : 0;
    ushort_t* C2 = (ushort_t*)w;     // only used when out_bf16
    float* sum1 = stats, *sq1 = stats + 512, *sum2 = stats + 1024, *sq2 = stats + 1536;

    stage1_kernel<<<1537, 256, 0, stream>>>(xyzF, cenF, W1f, W2f, W2c,
                                            idxb, wb, stats, H4, H8, H12, G);
    greduce_kernel<<<512, 256, 0, stream>>>((float4*)G);
    blend1<<<P_ / 32, 256, 0, stream>>>(G, idxb, wb, C1, sum1, sq1);
    gemm2_fused<<<dim3(P_ / 128, 2), 512, 0, stream>>>(C1, W2c, (float*)d_out, C2, out_bf16,
                                                       sum1, sq1, g1F, be1F, sum2, sq2);
    bn_apply_out<<<2048, 256, 0, stream>>>(C2, (float*)d_out, sum2, sq2,
                                           g2F, be2F, out_bf16);
}

// Round 13
// 210.656 us; speedup vs baseline: 1.0305x; 1.0305x over previous
//
#include <hip/hip_runtime.h>
#include <stdint.h>

#define S_   512
#define E_   512
#define CIN  1536
#define P_   32768
#define OUTC 512
#define LDP  40    // padded LDS row stride (shorts) for gemm_g register-staged tiles
#define LDA3 40    // gemm2 BK=32 A-tile stride (shorts): 32 + 8 pad -> 2-way-free b128
#define CST2 264   // gemm2 epilogue C-staging stride (shorts): 256 + 8
#define GSLAB ((size_t)4 * S_ * OUTC)   // one K-slab of G: [4 batches][512][512] fp32

typedef __attribute__((ext_vector_type(8))) short s16x8;   // MFMA A/B frag (8 bf16)
typedef __attribute__((ext_vector_type(4))) float f32x4;   // MFMA C/D frag
typedef unsigned short ushort_t;

__device__ __forceinline__ float b2f(uint32_t b) {
    union { uint32_t u; float f; } v; v.u = b << 16; return v.f;
}
__device__ __forceinline__ uint32_t f2b(float f) {   // fp32 -> bf16 bits, RNE
    union { float f; uint32_t u; } v; v.f = f;
    return (v.u + 0x7fffu + ((v.u >> 16) & 1u)) >> 16;
}
__device__ __forceinline__ uint4 cvt8(float4 a, float4 b) {
    uint4 r;
    r.x = f2b(a.x) | (f2b(a.y) << 16);
    r.y = f2b(a.z) | (f2b(a.w) << 16);
    r.z = f2b(b.x) | (f2b(b.y) << 16);
    r.w = f2b(b.z) | (f2b(b.w) << 16);
    return r;
}
__device__ __forceinline__ void async16(const void* g, void* l) {
    __builtin_amdgcn_global_load_lds(
        (const __attribute__((address_space(1))) void*)g,
        (__attribute__((address_space(3))) void*)l, 16, 0, 0);
}
// branchless top-3 insert
__device__ __forceinline__ void ins3(float d, int s,
                                     float& d0, int& i0, float& d1, int& i1,
                                     float& d2, int& i2)
{
    const bool c0 = d < d0, c1 = d < d1, c2 = d < d2;
    i2 = c1 ? i1 : (c2 ? s : i2);  d2 = c1 ? d1 : (c2 ? d : d2);
    i1 = c0 ? i0 : (c1 ? s : i1);  d1 = c0 ? d0 : (c1 ? d : d1);
    i0 = c0 ? s  : i0;             d0 = c0 ? d  : d0;
}

// ---------- 1) stage1: gemm_g ∥ W2-convert ∥ stats-zero ∥ kNN — one dispatch ----------
// Block map: [0,768) gemm_g | [768,1024) W2 cvt | 1024 stats zero | [1025,1537) kNN.
// gemm_g converts W1 inline and writes per-K-chunk slabs G0/G1/G2 with PLAIN stores.
__global__ __launch_bounds__(256) void stage1_kernel(
    const float* __restrict__ xyz, const float* __restrict__ centers,
    const float* __restrict__ W1f, const float* __restrict__ W2f,
    ushort_t* __restrict__ W2c,
    int* __restrict__ idx_out, float* __restrict__ w_out, float* __restrict__ stats,
    const float* __restrict__ H4, const float* __restrict__ H8,
    const float* __restrict__ H12, float* __restrict__ G)
{
    __shared__ float4 c4[S_];
    __shared__ ushort_t Asm[64 * LDP];
    __shared__ ushort_t Bsm[64 * LDP];
    const int blk = blockIdx.x;
    const int t   = threadIdx.x;

    if (blk < 768) {
        // ================= gemm_g role: G_ck[b] = H_ck[b] x W1_ck^T =================
        const int gblk = blk;                   // 0..767
        const int bz = gblk >> 6;               // 0..11  (bb*3 + ck)
        const int rem = gblk & 63;
        const int colBase = (rem & 7) * 64, rowBase = (rem >> 3) * 64;
        const int bb = bz / 3, ck = bz - bb * 3;
        const float* Hs = (ck == 0 ? H4 : (ck == 1) ? H8 : H12) + (size_t)bb * S_ * E_;
        const int kOff = ck * 512;
        const int wave = t >> 6, lane = t & 63;
        const int wr = wave >> 1, wc = wave & 1, quad = lane >> 4, l15 = lane & 15;

        f32x4 acc[2][2];
        const f32x4 z4 = {0.f, 0.f, 0.f, 0.f};
#pragma unroll
        for (int i = 0; i < 2; ++i)
#pragma unroll
            for (int j = 0; j < 2; ++j) acc[i][j] = z4;

        const int ar = t >> 2, ac = (t & 3) * 8;

        float4 A0a, A0b, B0a, B0b;
        auto loadTile = [&](int k0) {
            const int kc = k0 + ac;
            const float* r0 = Hs + (size_t)(rowBase + ar) * E_ + kc;
            A0a = *(const float4*)r0;  A0b = *(const float4*)(r0 + 4);
            const float* w0 = W1f + (size_t)(colBase + ar) * CIN + kOff + kc;
            B0a = *(const float4*)w0;  B0b = *(const float4*)(w0 + 4);
        };
        loadTile(0);

        for (int k0 = 0; k0 < 512; k0 += 32) {
            __syncthreads();
            *(uint4*)&Asm[ar * LDP + ac] = cvt8(A0a, A0b);
            *(uint4*)&Bsm[ar * LDP + ac] = cvt8(B0a, B0b);
            __syncthreads();
            if (k0 + 32 < 512) loadTile(k0 + 32);

            s16x8 af[2], bfr[2];
#pragma unroll
            for (int mi = 0; mi < 2; ++mi)
                af[mi] = *(const s16x8*)&Asm[(wr * 32 + mi * 16 + l15) * LDP + quad * 8];
#pragma unroll
            for (int ni = 0; ni < 2; ++ni)
                bfr[ni] = *(const s16x8*)&Bsm[(wc * 32 + ni * 16 + l15) * LDP + quad * 8];
#pragma unroll
            for (int mi = 0; mi < 2; ++mi)
#pragma unroll
                for (int ni = 0; ni < 2; ++ni)
                    acc[mi][ni] = __builtin_amdgcn_mfma_f32_16x16x32_bf16(
                        af[mi], bfr[ni], acc[mi][ni], 0, 0, 0);
        }

        float* Gs = G + (size_t)ck * GSLAB;
#pragma unroll
        for (int mi = 0; mi < 2; ++mi) {
            const int row0 = rowBase + wr * 32 + mi * 16 + quad * 4;
#pragma unroll
            for (int ni = 0; ni < 2; ++ni) {
                const int col = colBase + wc * 32 + ni * 16 + l15;
#pragma unroll
                for (int r = 0; r < 4; ++r)
                    Gs[((size_t)bb * S_ + row0 + r) * OUTC + col] = acc[mi][ni][r];
            }
        }
        return;
    }

    if (blk < 1025) {
        if (blk < 1024) {          // W2: 65536 vec4 over 256 blocks
            const int v = (blk - 768) * 256 + t;
            const float4 x = ((const float4*)W2f)[v];
            uint2 o; o.x = f2b(x.x) | (f2b(x.y) << 16); o.y = f2b(x.z) | (f2b(x.w) << 16);
            ((uint2*)W2c)[v] = o;
        } else {                   // blk == 1024: zero 2048-float stats
#pragma unroll
            for (int i = 0; i < 8; ++i) stats[t * 8 + i] = 0.f;
        }
        return;
    }

    // ================= kNN role: 4 lanes/point, dual top-3 chains =================
    const int pBlock = (blk - 1025) * 64;
    const int b = pBlock >> 13;
    for (int i = t; i < S_; i += 256) {
        const float x = centers[(size_t)(b * S_ + i) * 3 + 0];
        const float y = centers[(size_t)(b * S_ + i) * 3 + 1];
        const float z = centers[(size_t)(b * S_ + i) * 3 + 2];
        float4 v; v.x = x; v.y = y; v.z = z; v.w = x * x + y * y + z * z;
        c4[i] = v;
    }
    __syncthreads();

    const int l4 = t & 3, pi = t >> 2;
    const int p = pBlock + pi;
    const float x = xyz[(size_t)p * 3 + 0];
    const float y = xyz[(size_t)p * 3 + 1];
    const float z = xyz[(size_t)p * 3 + 2];
    const float xx = x * x + y * y + z * z;

    float d0 = 3e38f, d1 = 3e38f, d2 = 3e38f;
    int   i0 = 0,     i1 = 0,     i2 = 0;
    float e0 = 3e38f, e1 = 3e38f, e2 = 3e38f;
    int   f0 = 0,     f1 = 0,     f2 = 0;
#pragma unroll 2
    for (int j = 0; j < 128; j += 2) {
        const int sA = 4 * j + l4;
        const int sB = sA + 4;
        const float4 cA = c4[sA];
        const float4 cB = c4[sB];
        const float dotA = x * cA.x + y * cA.y + z * cA.z;
        const float dotB = x * cB.x + y * cB.y + z * cB.z;
        const float dA = (xx - 2.0f * dotA) + cA.w;   // mirror np association
        const float dB = (xx - 2.0f * dotB) + cB.w;
        ins3(dA, sA, d0, i0, d1, i1, d2, i2);
        ins3(dB, sB, e0, f0, e1, f1, e2, f2);
    }
    ins3(e0, f0, d0, i0, d1, i1, d2, i2);
    ins3(e1, f1, d0, i0, d1, i1, d2, i2);
    ins3(e2, f2, d0, i0, d1, i1, d2, i2);
#pragma unroll
    for (int m = 1; m <= 2; m <<= 1) {
        const float od0 = __shfl_xor(d0, m), od1 = __shfl_xor(d1, m), od2 = __shfl_xor(d2, m);
        const int   oi0 = __shfl_xor(i0, m), oi1 = __shfl_xor(i1, m), oi2 = __shfl_xor(i2, m);
        ins3(od0, oi0, d0, i0, d1, i1, d2, i2);
        ins3(od1, oi1, d0, i0, d1, i1, d2, i2);
        ins3(od2, oi2, d0, i0, d1, i1, d2, i2);
    }
    if (l4 == 0) {
        const float r0 = 1.0f / (d0 + 1e-8f);
        const float r1 = 1.0f / (d1 + 1e-8f);
        const float r2 = 1.0f / (d2 + 1e-8f);
        const float rs = r0 + r1 + r2;
        idx_out[p * 3 + 0] = i0; idx_out[p * 3 + 1] = i1; idx_out[p * 3 + 2] = i2;
        w_out[p * 3 + 0] = r0 / rs; w_out[p * 3 + 1] = r1 / rs; w_out[p * 3 + 2] = r2 / rs;
    }
}

// ---------- 2) greduce: G0 += G1 + G2 (dense, coalesced; 12 MB read + 4 MB write) ----------
__global__ __launch_bounds__(256) void greduce_kernel(float4* __restrict__ G)
{
    const float4* G1 = G + GSLAB / 4;
    const float4* G2 = G + 2 * (GSLAB / 4);
    const size_t v0 = ((size_t)blockIdx.x * 256 + threadIdx.x) * 2;
#pragma unroll
    for (int i = 0; i < 2; ++i) {
        const size_t v = v0 + i;
        float4 a = G[v];
        const float4 b = G1[v];
        const float4 c = G2[v];
        a.x += b.x + c.x; a.y += b.y + c.y; a.z += b.z + c.z; a.w += b.w + c.w;
        G[v] = a;
    }
}

// ---------- 3) blend: C1raw[p] = sum_k w_k * G[b,i_k] (fp32) -> bf16 + BN1 stats ----------
// r11 form (session best): 512 blocks x 64 points = 2 blocks/CU.
__global__ __launch_bounds__(256) void blend1(
    const float* __restrict__ G, const int* __restrict__ idx, const float* __restrict__ wgt,
    ushort_t* __restrict__ C1, float* __restrict__ gsum, float* __restrict__ gsq)
{
    __shared__ float reds[512], redq[512];
    const int t = threadIdx.x;
    const int cg = t & 63, pr = t >> 6;
    const int ch0 = cg * 8;
    const int pBase = blockIdx.x * 64;

    float s[8], q[8];
#pragma unroll
    for (int e = 0; e < 8; ++e) { s[e] = 0.f; q[e] = 0.f; }

    for (int j = 0; j < 16; ++j) {
        const int p = pBase + j * 4 + pr;
        const int b = p >> 13;
        const int i0 = idx[p * 3 + 0], i1 = idx[p * 3 + 1], i2 = idx[p * 3 + 2];
        const float w0 = wgt[p * 3 + 0], w1 = wgt[p * 3 + 1], w2 = wgt[p * 3 + 2];
        const float* g0 = G + ((size_t)b * S_ + i0) * OUTC + ch0;
        const float* g1 = G + ((size_t)b * S_ + i1) * OUTC + ch0;
        const float* g2 = G + ((size_t)b * S_ + i2) * OUTC + ch0;
        float c[8];
        uint32_t od[4];
#pragma unroll
        for (int e = 0; e < 8; ++e) {
            c[e] = w0 * g0[e] + w1 * g1[e] + w2 * g2[e];
            s[e] += c[e]; q[e] += c[e] * c[e];
        }
#pragma unroll
        for (int e = 0; e < 4; ++e) od[e] = f2b(c[2 * e]) | (f2b(c[2 * e + 1]) << 16);
        uint4 o; o.x = od[0]; o.y = od[1]; o.z = od[2]; o.w = od[3];
        *(uint4*)(C1 + (size_t)p * OUTC + ch0) = o;
    }

    for (int i = t; i < 512; i += 256) { reds[i] = 0.f; redq[i] = 0.f; }
    __syncthreads();
#pragma unroll
    for (int e = 0; e < 8; ++e) {
        atomicAdd(&reds[ch0 + e], s[e]);
        atomicAdd(&redq[ch0 + e], q[e]);
    }
    __syncthreads();
    for (int i = t; i < 512; i += 256) {
        atomicAdd(&gsum[i], reds[i]);
        atomicAdd(&gsq[i],  redq[i]);
    }
}

// ---------- 4) GEMM2: BK=32 double-buffered pipeline (r9/r11 exact) ----------
__global__ __launch_bounds__(512, 4) void gemm2_fused(
    const ushort_t* __restrict__ Araw, const ushort_t* __restrict__ Bw,
    float* __restrict__ outF, ushort_t* __restrict__ outB, int out_bf16,
    const float* __restrict__ gsum1, const float* __restrict__ gsq1,
    const float* __restrict__ g1, const float* __restrict__ be1,
    float* __restrict__ gsum2, float* __restrict__ gsq2)
{
    __shared__ __align__(16) ushort_t sbuf[26624];
    __shared__ float sc1[512], sh1[512];
    __shared__ float red[512];
    ushort_t* const Asm0 = sbuf;
    ushort_t* const Asm1 = sbuf + 5120;
    ushort_t* const Bsm0 = sbuf + 10240;
    ushort_t* const Bsm1 = sbuf + 18432;

    const int K = 512, Nn = 512;
    const int t = threadIdx.x, wave = t >> 6, lane = t & 63;
    const int wr = wave >> 2, wc = wave & 3, quad = lane >> 4, l15 = lane & 15;
    const int rowBase = blockIdx.x * 128, colBase = blockIdx.y * 256;

    {
        const float inv = 1.0f / (float)P_;
        const float mean = gsum1[t] * inv;
        const float var  = gsq1[t] * inv - mean * mean;
        const float s    = g1[t] * rsqrtf(var + 1e-5f);
        sc1[t] = s; sh1[t] = be1[t] - mean * s;
    }

    f32x4 acc[4][4];
    const f32x4 z4 = {0.f, 0.f, 0.f, 0.f};
#pragma unroll
    for (int i = 0; i < 4; ++i)
#pragma unroll
        for (int j = 0; j < 4; ++j) acc[i][j] = z4;

    const int ar  = t >> 2;
    const int ac8 = (t & 3) * 8;
    const ushort_t* Ab = Araw + (size_t)rowBase * K;

    // B DMA: 2 issues/thread/step; XOR class (row>>1)&3 == (lane>>3)&3 for both issues.
    const int brow = wave * 32 + (lane >> 2);
    const int bq8  = ((lane & 3) ^ ((lane >> 3) & 3)) * 8;
    const int bdst = wave * 1024 + lane * 8;
    const ushort_t* Bb = Bw + (size_t)colBase * K;

    auto xform = [&](const uint4 a, const int k0n, ushort_t* dst) {
        const int c0 = k0n + ac8;
        const float4 sa = *(const float4*)&sc1[c0], sb = *(const float4*)&sc1[c0 + 4];
        const float4 ha = *(const float4*)&sh1[c0], hb = *(const float4*)&sh1[c0 + 4];
        const float y0 = fmaxf(0.f, b2f(a.x & 0xffffu) * sa.x + ha.x);
        const float y1 = fmaxf(0.f, b2f(a.x >> 16)     * sa.y + ha.y);
        const float y2 = fmaxf(0.f, b2f(a.y & 0xffffu) * sa.z + ha.z);
        const float y3 = fmaxf(0.f, b2f(a.y >> 16)     * sa.w + ha.w);
        const float y4 = fmaxf(0.f, b2f(a.z & 0xffffu) * sb.x + hb.x);
        const float y5 = fmaxf(0.f, b2f(a.z >> 16)     * sb.y + hb.y);
        const float y6 = fmaxf(0.f, b2f(a.w & 0xffffu) * sb.z + hb.z);
        const float y7 = fmaxf(0.f, b2f(a.w >> 16)     * sb.w + hb.w);
        uint4 u;
        u.x = f2b(y0) | (f2b(y1) << 16); u.y = f2b(y2) | (f2b(y3) << 16);
        u.z = f2b(y4) | (f2b(y5) << 16); u.w = f2b(y6) | (f2b(y7) << 16);
        *(uint4*)&dst[ar * LDA3 + ac8] = u;
    };

    uint4 aA = *(const uint4*)(Ab + (size_t)ar * K + ac8);
    __syncthreads();

    async16(Bb + (size_t)brow * K + bq8,        Bsm0 + bdst);
    async16(Bb + (size_t)(brow + 16) * K + bq8, Bsm0 + bdst + 512);
    xform(aA, 0, Asm0);
    uint4 aB = *(const uint4*)(Ab + (size_t)ar * K + 32 + ac8);
    __syncthreads();

#pragma unroll
    for (int k = 0; k < 16; ++k) {
        ushort_t* const Asmb = (k & 1) ? Asm1 : Asm0;
        ushort_t* const Bsmb = (k & 1) ? Bsm1 : Bsm0;
        ushort_t* const AsmN = (k & 1) ? Asm0 : Asm1;
        ushort_t* const BsmN = (k & 1) ? Bsm0 : Bsm1;
        if (k < 15) {
            const int k0n = (k + 1) * 32;
            async16(Bb + (size_t)brow * K + k0n + bq8,        BsmN + bdst);
            async16(Bb + (size_t)(brow + 16) * K + k0n + bq8, BsmN + bdst + 512);
            if (k < 14) {
                const int k0p = (k + 2) * 32;
                if (k & 1) aB = *(const uint4*)(Ab + (size_t)ar * K + k0p + ac8);
                else       aA = *(const uint4*)(Ab + (size_t)ar * K + k0p + ac8);
            }
            xform((k & 1) ? aA : aB, k0n, AsmN);
        }
        s16x8 af[4], bfr[4];
#pragma unroll
        for (int mi = 0; mi < 4; ++mi)
            af[mi] = *(const s16x8*)&Asmb[(wr * 64 + mi * 16 + l15) * LDA3 + quad * 8];
#pragma unroll
        for (int ni = 0; ni < 4; ++ni) {
            const int r = wc * 64 + ni * 16 + l15;
            bfr[ni] = *(const s16x8*)&Bsmb[r * 32 + ((quad ^ ((r >> 1) & 3)) << 3)];
        }
#pragma unroll
        for (int mi = 0; mi < 4; ++mi)
#pragma unroll
            for (int ni = 0; ni < 4; ++ni)
                acc[mi][ni] = __builtin_amdgcn_mfma_f32_16x16x32_bf16(
                    af[mi], bfr[ni], acc[mi][ni], 0, 0, 0);
        __syncthreads();
    }

    // ---- BN2 stats (cols colBase..colBase+255) ----
    red[t] = 0.f;
    __syncthreads();
#pragma unroll
    for (int ni = 0; ni < 4; ++ni) {
        float s = 0.f, q = 0.f;
#pragma unroll
        for (int mi = 0; mi < 4; ++mi)
#pragma unroll
            for (int r = 0; r < 4; ++r) { const float v = acc[mi][ni][r]; s += v; q += v * v; }
        const int cl = wc * 64 + ni * 16 + l15;
        atomicAdd(&red[cl], s);
        atomicAdd(&red[256 + cl], q);
    }
    __syncthreads();
    if (t < 256) atomicAdd(&gsum2[colBase + t], red[t]);
    else         atomicAdd(&gsq2[colBase + (t - 256)], red[t]);

    // ---- store: LDS-staged coalesced (bf16 path) ----
    if (out_bf16) {
        ushort_t* cst = sbuf;
        const int rr = t >> 3, seg = t & 7;
#pragma unroll
        for (int c = 0; c < 2; ++c) {
            __syncthreads();
            if (wr == c) {
#pragma unroll
                for (int mi = 0; mi < 4; ++mi)
#pragma unroll
                    for (int ni = 0; ni < 4; ++ni)
#pragma unroll
                        for (int r = 0; r < 4; ++r)
                            cst[(mi * 16 + quad * 4 + r) * CST2 + wc * 64 + ni * 16 + l15] =
                                (ushort_t)f2b(acc[mi][ni][r]);
            }
            __syncthreads();
            const size_t gbase = (size_t)(rowBase + c * 64 + rr) * Nn + colBase;
#pragma unroll
            for (int i = 0; i < 4; ++i) {
                const int cc = seg + i * 8;
                const uint4 v = *(const uint4*)&cst[rr * CST2 + cc * 8];
                *(uint4*)(outB + gbase + cc * 8) = v;
            }
        }
    } else {
#pragma unroll
        for (int mi = 0; mi < 4; ++mi) {
            const int row0 = rowBase + wr * 64 + mi * 16 + quad * 4;
#pragma unroll
            for (int ni = 0; ni < 4; ++ni) {
                const int col = colBase + wc * 64 + ni * 16 + l15;
#pragma unroll
                for (int r = 0; r < 4; ++r)
                    outF[(size_t)(row0 + r) * Nn + col] = acc[mi][ni][r];
            }
        }
    }
}

// ---------- 5) BN2 finalize + apply + ReLU -> d_out fp32 (grid-stride, 2048 blocks) ----------
__global__ __launch_bounds__(256) void bn_apply_out(
    const ushort_t* __restrict__ C2, float* __restrict__ Y,
    const float* __restrict__ gsum, const float* __restrict__ gsq,
    const float* __restrict__ gamma, const float* __restrict__ beta, int from_bf16)
{
    __shared__ float sc[512], sh[512];
    const int t = threadIdx.x;
    const float inv = 1.0f / (float)P_;
    for (int i = t; i < 512; i += 256) {
        const float mean = gsum[i] * inv;
        const float var  = gsq[i] * inv - mean * mean;
        const float s    = gamma[i] * rsqrtf(var + 1e-5f);
        sc[i] = s; sh[i] = beta[i] - mean * s;
    }
    __syncthreads();
    const size_t total = (size_t)P_ * OUTC / 8;
    for (size_t v = (size_t)blockIdx.x * 256 + t; v < total; v += (size_t)2048 * 256) {
        const int ch = (int)((v * 8) & 511);
        float4 u0, u1;
        if (from_bf16) {
            const uint4 xv = ((const uint4*)C2)[v];
            u0.x = b2f(xv.x & 0xffffu); u0.y = b2f(xv.x >> 16);
            u0.z = b2f(xv.y & 0xffffu); u0.w = b2f(xv.y >> 16);
            u1.x = b2f(xv.z & 0xffffu); u1.y = b2f(xv.z >> 16);
            u1.z = b2f(xv.w & 0xffffu); u1.w = b2f(xv.w >> 16);
        } else {
            u0 = ((const float4*)Y)[v * 2];
            u1 = ((const float4*)Y)[v * 2 + 1];
        }
        u0.x = fmaxf(0.f, u0.x * sc[ch + 0] + sh[ch + 0]);
        u0.y = fmaxf(0.f, u0.y * sc[ch + 1] + sh[ch + 1]);
        u0.z = fmaxf(0.f, u0.z * sc[ch + 2] + sh[ch + 2]);
        u0.w = fmaxf(0.f, u0.w * sc[ch + 3] + sh[ch + 3]);
        u1.x = fmaxf(0.f, u1.x * sc[ch + 4] + sh[ch + 4]);
        u1.y = fmaxf(0.f, u1.y * sc[ch + 5] + sh[ch + 5]);
        u1.z = fmaxf(0.f, u1.z * sc[ch + 6] + sh[ch + 6]);
        u1.w = fmaxf(0.f, u1.w * sc[ch + 7] + sh[ch + 7]);
        ((float4*)Y)[v * 2]     = u0;
        ((float4*)Y)[v * 2 + 1] = u1;
    }
}

// ---------- launch ----------
extern "C" void kernel_launch(void* const* d_in, const int* in_sizes, int n_in,
                              void* d_out, int out_size, void* d_ws, size_t ws_size,
                              hipStream_t stream)
{
    (void)in_sizes; (void)n_in; (void)out_size;
    const float* xyzF = (const float*)d_in[0];
    const float* cenF = (const float*)d_in[1];
    const float* H4   = (const float*)d_in[2];
    const float* H8   = (const float*)d_in[3];
    const float* H12  = (const float*)d_in[4];
    const float* W1f  = (const float*)d_in[5];
    // b1 (d_in[6]) / b2 (d_in[10]) cancel in BN mean subtraction
    const float* g1F  = (const float*)d_in[7];
    const float* be1F = (const float*)d_in[8];
    const float* W2f  = (const float*)d_in[9];
    const float* g2F  = (const float*)d_in[11];
    const float* be2F = (const float*)d_in[12];

    char* w = (char*)d_ws;
    float*    stats = (float*)w;     w += 2048 * 4;
    ushort_t* W2c   = (ushort_t*)w;  w += (size_t)OUTC * OUTC * 2;
    int*      idxb  = (int*)w;       w += (size_t)P_ * 3 * 4;
    float*    wb    = (float*)w;     w += (size_t)P_ * 3 * 4;
    float*    G     = (float*)w;     w += 3 * GSLAB * 4;               // 12 MB (3 K-slabs)
    ushort_t* C1    = (ushort_t*)w;  w += (size_t)P_ * OUTC * 2;       // 32 MB (raw, pre-BN)
    const size_t need1 = (size_t)(w - (char*)d_ws);
    const int out_bf16 = (ws_size >= need1 + (size_t)P_ * OUTC * 2) ? 1 : 0;
    ushort_t* C2 = (ushort_t*)w;     // only used when out_bf16
    float* sum1 = stats, *sq1 = stats + 512, *sum2 = stats + 1024, *sq2 = stats + 1536;

    stage1_kernel<<<1537, 256, 0, stream>>>(xyzF, cenF, W1f, W2f, W2c,
                                            idxb, wb, stats, H4, H8, H12, G);
    greduce_kernel<<<512, 256, 0, stream>>>((float4*)G);
    blend1<<<P_ / 64, 256, 0, stream>>>(G, idxb, wb, C1, sum1, sq1);
    gemm2_fused<<<dim3(P_ / 128, 2), 512, 0, stream>>>(C1, W2c, (float*)d_out, C2, out_bf16,
                                                       sum1, sq1, g1F, be1F, sum2, sq2);
    bn_apply_out<<<2048, 256, 0, stream>>>(C2, (float*)d_out, sum2, sq2,
                                           g2F, be2F, out_bf16);
}